// Round 1
// baseline (1224.958 us; speedup 1.0000x reference)
//
#include <hip/hip_runtime.h>
#include <math.h>

#define NUM_B 1024
#define LW 49
#define CD 384
#define NH 12
#define HD 32
#define SCALE_F 19.595917942265423f   // sqrt(384), faithful to reference

// ---------------------------------------------------------------------------
// bias[h][i][j] = rel_bias[rel_coords[i*49+j]*12 + h]   (H,L,L) fp32, 115 KB
// ---------------------------------------------------------------------------
__global__ void bias_precompute(const float* __restrict__ rel_bias,
                                const int* __restrict__ rel_coords,
                                float* __restrict__ bias) {
    int idx = blockIdx.x * 256 + threadIdx.x;
    if (idx >= NH * LW * LW) return;
    int h = idx / (LW * LW);
    int ij = idx - h * (LW * LW);
    bias[idx] = rel_bias[rel_coords[ij] * NH + h];
}

// ---------------------------------------------------------------------------
// QKV GEMM: C[m][n] = sum_k x[m][k]*qkv_w[n][k];  M=50176 N=1152 K=384
// Output scattered into q/k/v tensors with (B,H,L,hd) layout.
// 64x64 tile, BK=32, transposed LDS (As[k][m]) so micro-tile reads are b128.
// ---------------------------------------------------------------------------
__global__ __launch_bounds__(256) void qkv_gemm(const float* __restrict__ x,
                                                const float* __restrict__ w,
                                                float* __restrict__ qp,
                                                float* __restrict__ kp,
                                                float* __restrict__ vp) {
    __shared__ float As[32][68];   // [k][m], stride 68 keeps b128 aligned + conflict-lite
    __shared__ float Bs[32][68];   // [k][n]
    const int tid = threadIdx.x;
    const int m0 = blockIdx.x * 64;
    const int n0 = blockIdx.y * 64;
    const int tx = tid & 15;          // n micro-tile
    const int ty = tid >> 4;          // m micro-tile
    const int lr = tid >> 3;          // 0..31 load row
    const int lc = (tid & 7) << 2;    // 0..28 load k-col (float4)
    float acc[4][4] = {};
    for (int k0 = 0; k0 < CD; k0 += 32) {
        float4 a0 = *(const float4*)&x[(size_t)(m0 + lr) * CD + k0 + lc];
        float4 a1 = *(const float4*)&x[(size_t)(m0 + lr + 32) * CD + k0 + lc];
        float4 b0 = *(const float4*)&w[(size_t)(n0 + lr) * CD + k0 + lc];
        float4 b1 = *(const float4*)&w[(size_t)(n0 + lr + 32) * CD + k0 + lc];
        __syncthreads();
        As[lc + 0][lr] = a0.x; As[lc + 1][lr] = a0.y; As[lc + 2][lr] = a0.z; As[lc + 3][lr] = a0.w;
        As[lc + 0][lr + 32] = a1.x; As[lc + 1][lr + 32] = a1.y; As[lc + 2][lr + 32] = a1.z; As[lc + 3][lr + 32] = a1.w;
        Bs[lc + 0][lr] = b0.x; Bs[lc + 1][lr] = b0.y; Bs[lc + 2][lr] = b0.z; Bs[lc + 3][lr] = b0.w;
        Bs[lc + 0][lr + 32] = b1.x; Bs[lc + 1][lr + 32] = b1.y; Bs[lc + 2][lr + 32] = b1.z; Bs[lc + 3][lr + 32] = b1.w;
        __syncthreads();
#pragma unroll
        for (int k = 0; k < 32; ++k) {
            float4 av = *(const float4*)&As[k][ty << 2];
            float4 bv = *(const float4*)&Bs[k][tx << 2];
            acc[0][0] += av.x * bv.x; acc[0][1] += av.x * bv.y; acc[0][2] += av.x * bv.z; acc[0][3] += av.x * bv.w;
            acc[1][0] += av.y * bv.x; acc[1][1] += av.y * bv.y; acc[1][2] += av.y * bv.z; acc[1][3] += av.y * bv.w;
            acc[2][0] += av.z * bv.x; acc[2][1] += av.z * bv.y; acc[2][2] += av.z * bv.z; acc[2][3] += av.z * bv.w;
            acc[3][0] += av.w * bv.x; acc[3][1] += av.w * bv.y; acc[3][2] += av.w * bv.z; acc[3][3] += av.w * bv.w;
        }
    }
    // n -> (tensor t, head h, dim d); the 4 contiguous n share t/h, d..d+3
    const int nb = n0 + (tx << 2);
    const int t = nb / CD;
    const int rem = nb - t * CD;
    const int h = rem >> 5;
    const int d = rem & 31;
    float* outp = (t == 0) ? qp : (t == 1) ? kp : vp;
#pragma unroll
    for (int i = 0; i < 4; ++i) {
        int m = m0 + (ty << 2) + i;
        int b = m / LW;
        int l = m - b * LW;
        float4 v4 = make_float4(acc[i][0], acc[i][1], acc[i][2], acc[i][3]);
        *(float4*)&outp[((((size_t)b * NH + h) * LW + l) << 5) + d] = v4;
    }
}

// ---------------------------------------------------------------------------
// Attention: one block per (b,h). q,v in LDS; k-row-per-lane in registers.
// Wave-per-row: logits (fp32) + bias, mask (w = b&3) -> exactly -100.0,
// 64-lane shfl softmax, P.V from LDS. Output overwrites the q slice (block-
// exclusive region, safe).
// ---------------------------------------------------------------------------
__global__ __launch_bounds__(256) void attn_kernel(const float* qp,
                                                   const float* __restrict__ kp,
                                                   const float* __restrict__ vp,
                                                   const float* __restrict__ bias,
                                                   const int* __restrict__ mask,
                                                   float* aout) {
    const int bh = blockIdx.x;
    const int b = bh / NH;
    const int h = bh - b * NH;
    __shared__ float qs[LW][36];   // stride 36: b128-aligned broadcast reads
    __shared__ float vs[LW][33];   // stride 33: conflict-free scalar PV reads
    __shared__ float ps[4][56];
    const int tid = threadIdx.x;
    const int wv = tid >> 6;
    const int lane = tid & 63;
    const size_t base = (size_t)bh * (LW * HD);
    const float4* qg4 = (const float4*)(qp + base);
    const float4* vg4 = (const float4*)(vp + base);
    for (int idx = tid; idx < 392; idx += 256) {   // 392 float4 = 49*32 floats
        int l = idx >> 3;
        int d = (idx & 7) << 2;
        float4 qv = qg4[idx];
        qs[l][d] = qv.x; qs[l][d + 1] = qv.y; qs[l][d + 2] = qv.z; qs[l][d + 3] = qv.w;
        float4 vv = vg4[idx];
        vs[l][d] = vv.x; vs[l][d + 1] = vv.y; vs[l][d + 2] = vv.z; vs[l][d + 3] = vv.w;
    }
    float kreg[32];
    if (lane < LW) {
        const float4* kg4 = (const float4*)(kp + base + lane * HD);
#pragma unroll
        for (int r = 0; r < 8; ++r) *(float4*)&kreg[r * 4] = kg4[r];
    }
    __syncthreads();
    const float* bias_h = bias + h * (LW * LW);
    const int* mask_w = mask + (b & 3) * (LW * LW);
    for (int i = wv; i < LW; i += 4) {
        float s = -3.0e38f;
        if (lane < LW) {
            float a = 0.f;
#pragma unroll
            for (int r = 0; r < 8; ++r) {
                float4 qv = *(const float4*)&qs[i][r << 2];
                a += qv.x * kreg[r * 4 + 0] + qv.y * kreg[r * 4 + 1] +
                     qv.z * kreg[r * 4 + 2] + qv.w * kreg[r * 4 + 3];
            }
            s = a * SCALE_F + bias_h[i * LW + lane];
            if (mask_w[i * LW + lane] != 0) s = -100.0f;  // replace, per jnp.where
        }
        float mx = s;
#pragma unroll
        for (int off = 32; off > 0; off >>= 1) mx = fmaxf(mx, __shfl_xor(mx, off));
        float e = (lane < LW) ? __expf(s - mx) : 0.f;
        float sum = e;
#pragma unroll
        for (int off = 32; off > 0; off >>= 1) sum += __shfl_xor(sum, off);
        float p = e / sum;
        if (lane < LW) ps[wv][lane] = p;
        if (lane < HD) {
            float o = 0.f;
            for (int j = 0; j < LW; ++j) o += ps[wv][j] * vs[j][lane];
            aout[base + (size_t)i * HD + lane] = o;   // (B,H,L,hd) layout
        }
    }
}

// ---------------------------------------------------------------------------
// Proj GEMM: out[m][n] = sum_k attn[m][k]*proj_w[n][k] + proj_b[n]
// attn read from the q region with (B,H,L,hd) layout (k -> h=k/32, d=k%32).
// ---------------------------------------------------------------------------
__global__ __launch_bounds__(256) void proj_gemm(const float* __restrict__ attn,
                                                 const float* __restrict__ w,
                                                 const float* __restrict__ pb,
                                                 float* __restrict__ out) {
    __shared__ float As[32][68];
    __shared__ float Bs[32][68];
    const int tid = threadIdx.x;
    const int m0 = blockIdx.x * 64;
    const int n0 = blockIdx.y * 64;
    const int tx = tid & 15;
    const int ty = tid >> 4;
    const int lr = tid >> 3;
    const int lc = (tid & 7) << 2;
    const int m_a = m0 + lr;
    const int b_a = m_a / LW, l_a = m_a - b_a * LW;
    const int m_b = m0 + lr + 32;
    const int b_b = m_b / LW, l_b = m_b - b_b * LW;
    float acc[4][4] = {};
    for (int k0 = 0; k0 < CD; k0 += 32) {
        const int ha = k0 >> 5;
        float4 a0 = *(const float4*)&attn[((((size_t)b_a * NH + ha) * LW + l_a) << 5) + lc];
        float4 a1 = *(const float4*)&attn[((((size_t)b_b * NH + ha) * LW + l_b) << 5) + lc];
        float4 b0 = *(const float4*)&w[(size_t)(n0 + lr) * CD + k0 + lc];
        float4 b1 = *(const float4*)&w[(size_t)(n0 + lr + 32) * CD + k0 + lc];
        __syncthreads();
        As[lc + 0][lr] = a0.x; As[lc + 1][lr] = a0.y; As[lc + 2][lr] = a0.z; As[lc + 3][lr] = a0.w;
        As[lc + 0][lr + 32] = a1.x; As[lc + 1][lr + 32] = a1.y; As[lc + 2][lr + 32] = a1.z; As[lc + 3][lr + 32] = a1.w;
        Bs[lc + 0][lr] = b0.x; Bs[lc + 1][lr] = b0.y; Bs[lc + 2][lr] = b0.z; Bs[lc + 3][lr] = b0.w;
        Bs[lc + 0][lr + 32] = b1.x; Bs[lc + 1][lr + 32] = b1.y; Bs[lc + 2][lr + 32] = b1.z; Bs[lc + 3][lr + 32] = b1.w;
        __syncthreads();
#pragma unroll
        for (int k = 0; k < 32; ++k) {
            float4 av = *(const float4*)&As[k][ty << 2];
            float4 bv = *(const float4*)&Bs[k][tx << 2];
            acc[0][0] += av.x * bv.x; acc[0][1] += av.x * bv.y; acc[0][2] += av.x * bv.z; acc[0][3] += av.x * bv.w;
            acc[1][0] += av.y * bv.x; acc[1][1] += av.y * bv.y; acc[1][2] += av.y * bv.z; acc[1][3] += av.y * bv.w;
            acc[2][0] += av.z * bv.x; acc[2][1] += av.z * bv.y; acc[2][2] += av.z * bv.z; acc[2][3] += av.z * bv.w;
            acc[3][0] += av.w * bv.x; acc[3][1] += av.w * bv.y; acc[3][2] += av.w * bv.z; acc[3][3] += av.w * bv.w;
        }
    }
    float4 bias4 = *(const float4*)&pb[n0 + (tx << 2)];
#pragma unroll
    for (int i = 0; i < 4; ++i) {
        int m = m0 + (ty << 2) + i;
        float4 v4 = make_float4(acc[i][0] + bias4.x, acc[i][1] + bias4.y,
                                acc[i][2] + bias4.z, acc[i][3] + bias4.w);
        *(float4*)&out[(size_t)m * CD + n0 + (tx << 2)] = v4;
    }
}

// ---------------------------------------------------------------------------
extern "C" void kernel_launch(void* const* d_in, const int* in_sizes, int n_in,
                              void* d_out, int out_size, void* d_ws, size_t ws_size,
                              hipStream_t stream) {
    const float* x         = (const float*)d_in[0];
    const int*   mask      = (const int*)d_in[1];
    const float* qkv_w     = (const float*)d_in[2];
    const float* proj_w    = (const float*)d_in[3];
    const float* proj_b    = (const float*)d_in[4];
    const float* rel_bias  = (const float*)d_in[5];
    const int*   rel_coords= (const int*)d_in[6];
    float* out = (float*)d_out;

    // ws layout (fp32): q | k | v | bias  = 3*19,267,584 + 28,812 floats ~ 231.4 MB
    const size_t S = (size_t)NUM_B * NH * LW * HD;
    float* qp = (float*)d_ws;
    float* kp = qp + S;
    float* vp = kp + S;
    float* bias = vp + S;

    bias_precompute<<<dim3((NH * LW * LW + 255) / 256), dim3(256), 0, stream>>>(rel_bias, rel_coords, bias);
    qkv_gemm<<<dim3(784, 18), dim3(256), 0, stream>>>(x, qkv_w, qp, kp, vp);
    // attn output overwrites the q region (each block owns its (b,h) slice)
    attn_kernel<<<dim3(NUM_B * NH), dim3(256), 0, stream>>>(qp, kp, vp, bias, mask, qp);
    proj_gemm<<<dim3(784, 6), dim3(256), 0, stream>>>(qp, proj_w, proj_b, out);
}

// Round 2
// 734.153 us; speedup vs baseline: 1.6685x; 1.6685x over previous
//
#include <hip/hip_runtime.h>
#include <math.h>

#define NUM_B 1024
#define LW 49
#define CD 384
#define NH 12
#define HD 32
#define SCALE_F 19.595917942265423f   // sqrt(384), faithful to reference

typedef unsigned short u16;
typedef __attribute__((ext_vector_type(8))) short short8;   // 8 bf16 in 4 VGPRs
typedef __attribute__((ext_vector_type(4))) float floatx4;  // MFMA accumulator

static __device__ __forceinline__ u16 f2bf(float f) {       // RNE f32->bf16
    unsigned u = __float_as_uint(f);
    u += 0x7fffu + ((u >> 16) & 1u);
    return (u16)(u >> 16);
}
static __device__ __forceinline__ float bf2f(u16 s) {
    return __uint_as_float(((unsigned)s) << 16);
}

// ---------------------------------------------------------------------------
// Split fp32 -> (hi, lo) bf16.  hi=RNE(f), lo=RNE(f-hi): residual ~2^-17 rel.
// ---------------------------------------------------------------------------
__global__ __launch_bounds__(256) void convert_hilo(const float* __restrict__ src,
                                                    u16* __restrict__ hi,
                                                    u16* __restrict__ lo,
                                                    int n4) {
    int idx = blockIdx.x * 256 + threadIdx.x;
    if (idx >= n4) return;
    float4 v = ((const float4*)src)[idx];
    ushort4 h, l;
    h.x = f2bf(v.x); l.x = f2bf(v.x - bf2f(h.x));
    h.y = f2bf(v.y); l.y = f2bf(v.y - bf2f(h.y));
    h.z = f2bf(v.z); l.z = f2bf(v.z - bf2f(h.z));
    h.w = f2bf(v.w); l.w = f2bf(v.w - bf2f(h.w));
    ((ushort4*)hi)[idx] = h;
    ((ushort4*)lo)[idx] = l;
}

// ---------------------------------------------------------------------------
// bias[h][i][j] = rel_bias[rel_coords[i*49+j]*12 + h]
// ---------------------------------------------------------------------------
__global__ void bias_precompute(const float* __restrict__ rel_bias,
                                const int* __restrict__ rel_coords,
                                float* __restrict__ bias) {
    int idx = blockIdx.x * 256 + threadIdx.x;
    if (idx >= NH * LW * LW) return;
    int h = idx / (LW * LW);
    int ij = idx - h * (LW * LW);
    bias[idx] = rel_bias[rel_coords[ij] * NH + h];
}

// ---------------------------------------------------------------------------
// Split-bf16 MFMA GEMM: C[m][n] = sum_k A[m][k]*W[n][k], K=384.
// A,W pre-split into bf16 hi/lo; acc = hi*hi + hi*lo + lo*hi (3 MFMA).
// 128x128 tile, BK=32, global_load_lds(16B) staging, ds_read_b128 frags.
// MODE 0: scatter to q/k/v in (B,H,L,hd) fp32.  MODE 1: out[m][n] = acc + pb[n].
// ---------------------------------------------------------------------------
template<int MODE>
__global__ __launch_bounds__(256) void mfma_gemm(const u16* __restrict__ Ah,
                                                 const u16* __restrict__ Al,
                                                 const u16* __restrict__ Wh,
                                                 const u16* __restrict__ Wl,
                                                 const float* __restrict__ pb,
                                                 float* __restrict__ q,
                                                 float* __restrict__ k,
                                                 float* __restrict__ v) {
    __shared__ u16 As_h[128 * 32];   // [m][k] row-major, 64 B rows
    __shared__ u16 As_l[128 * 32];
    __shared__ u16 Bs_h[128 * 32];   // [n][k]
    __shared__ u16 Bs_l[128 * 32];
    const int tid = threadIdx.x;
    const int w = tid >> 6;
    const int lane = tid & 63;
    const int m0 = blockIdx.x * 128;
    const int n0 = blockIdx.y * 128;
    const int quad = lane >> 4;
    const int lc = lane & 15;
    const int wrow = (w >> 1) << 6;       // wave's 64-row origin
    const int wcol = (w & 1) << 6;        // wave's 64-col origin
    const int srow = lane >> 2;           // staging: row within 16-row chunk
    const int sch = (lane & 3) * 8;       // staging: k-chunk (shorts)

    floatx4 acc[4][4];
#pragma unroll
    for (int a = 0; a < 4; ++a)
#pragma unroll
        for (int b = 0; b < 4; ++b) acc[a][b] = (floatx4){0.f, 0.f, 0.f, 0.f};

    for (int k0 = 0; k0 < CD; k0 += 32) {
        __syncthreads();   // all waves done reading LDS from previous iter
#pragma unroll
        for (int i = 0; i < 2; ++i) {
            const int rb = w * 32 + i * 16;          // wave-uniform row base
            const size_t ga = (size_t)(m0 + rb + srow) * CD + k0 + sch;
            const size_t gb = (size_t)(n0 + rb + srow) * CD + k0 + sch;
            const int lof = rb * 32;                 // wave-uniform LDS base
            __builtin_amdgcn_global_load_lds(
                (const __attribute__((address_space(1))) void*)(Ah + ga),
                (__attribute__((address_space(3))) void*)(As_h + lof), 16, 0, 0);
            __builtin_amdgcn_global_load_lds(
                (const __attribute__((address_space(1))) void*)(Al + ga),
                (__attribute__((address_space(3))) void*)(As_l + lof), 16, 0, 0);
            __builtin_amdgcn_global_load_lds(
                (const __attribute__((address_space(1))) void*)(Wh + gb),
                (__attribute__((address_space(3))) void*)(Bs_h + lof), 16, 0, 0);
            __builtin_amdgcn_global_load_lds(
                (const __attribute__((address_space(1))) void*)(Wl + gb),
                (__attribute__((address_space(3))) void*)(Bs_l + lof), 16, 0, 0);
        }
        __syncthreads();   // vmcnt(0) drain: staged data visible

        short8 af_h[4], af_l[4], bf_h[4], bf_l[4];
#pragma unroll
        for (int t = 0; t < 4; ++t) {
            const int ar = (wrow + t * 16 + lc) * 32 + quad * 8;
            af_h[t] = *(const short8*)(As_h + ar);
            af_l[t] = *(const short8*)(As_l + ar);
            const int br = (wcol + t * 16 + lc) * 32 + quad * 8;
            bf_h[t] = *(const short8*)(Bs_h + br);
            bf_l[t] = *(const short8*)(Bs_l + br);
        }
#pragma unroll
        for (int tm = 0; tm < 4; ++tm)
#pragma unroll
            for (int tn = 0; tn < 4; ++tn) {
                acc[tm][tn] = __builtin_amdgcn_mfma_f32_16x16x32_bf16(af_h[tm], bf_h[tn], acc[tm][tn], 0, 0, 0);
                acc[tm][tn] = __builtin_amdgcn_mfma_f32_16x16x32_bf16(af_h[tm], bf_l[tn], acc[tm][tn], 0, 0, 0);
                acc[tm][tn] = __builtin_amdgcn_mfma_f32_16x16x32_bf16(af_l[tm], bf_h[tn], acc[tm][tn], 0, 0, 0);
            }
    }

    // D layout: col = lane&15, row = quad*4 + reg (verified m89/m91)
    if (MODE == 0) {
#pragma unroll
        for (int tn = 0; tn < 4; ++tn) {
            const int nst = n0 + wcol + tn * 16;
            const int t = nst / CD;
            const int rem = nst - t * CD;
            const int h = rem >> 5;
            const int db = (rem & 31) + lc;
            float* outp = (t == 0) ? q : (t == 1) ? k : v;
#pragma unroll
            for (int tm = 0; tm < 4; ++tm)
#pragma unroll
                for (int r = 0; r < 4; ++r) {
                    const int m = m0 + wrow + tm * 16 + quad * 4 + r;
                    const int b = m / LW;
                    const int l = m - b * LW;
                    outp[((((size_t)b * NH + h) * LW + l) << 5) + db] = acc[tm][tn][r];
                }
        }
    } else {
#pragma unroll
        for (int tn = 0; tn < 4; ++tn) {
            const int n = n0 + wcol + tn * 16 + lc;
            const float bias = pb[n];
#pragma unroll
            for (int tm = 0; tm < 4; ++tm)
#pragma unroll
                for (int r = 0; r < 4; ++r) {
                    const int m = m0 + wrow + tm * 16 + quad * 4 + r;
                    q[(size_t)m * CD + n] = acc[tm][tn][r] + bias;
                }
        }
    }
}

// ---------------------------------------------------------------------------
// Attention: one block per (b,h). q,v in LDS; k-row-per-lane in registers.
// fp32 logits + bias, mask -> exactly -100.0, 64-lane shfl softmax, P.V.
// Output written as bf16 hi/lo in [m][C] layout (c = h*32+d) for proj GEMM.
// ---------------------------------------------------------------------------
__global__ __launch_bounds__(256) void attn_kernel(const float* __restrict__ qp,
                                                   const float* __restrict__ kp,
                                                   const float* __restrict__ vp,
                                                   const float* __restrict__ bias,
                                                   const int* __restrict__ mask,
                                                   u16* __restrict__ aoh,
                                                   u16* __restrict__ aol) {
    const int bh = blockIdx.x;
    const int b = bh / NH;
    const int h = bh - b * NH;
    __shared__ float qs[LW][36];
    __shared__ float vs[LW][33];
    __shared__ float ps[4][56];
    const int tid = threadIdx.x;
    const int wv = tid >> 6;
    const int lane = tid & 63;
    const size_t base = (size_t)bh * (LW * HD);
    const float4* qg4 = (const float4*)(qp + base);
    const float4* vg4 = (const float4*)(vp + base);
    for (int idx = tid; idx < 392; idx += 256) {
        int l = idx >> 3;
        int d = (idx & 7) << 2;
        float4 qv = qg4[idx];
        qs[l][d] = qv.x; qs[l][d + 1] = qv.y; qs[l][d + 2] = qv.z; qs[l][d + 3] = qv.w;
        float4 vv = vg4[idx];
        vs[l][d] = vv.x; vs[l][d + 1] = vv.y; vs[l][d + 2] = vv.z; vs[l][d + 3] = vv.w;
    }
    float kreg[32];
    if (lane < LW) {
        const float4* kg4 = (const float4*)(kp + base + lane * HD);
#pragma unroll
        for (int r = 0; r < 8; ++r) *(float4*)&kreg[r * 4] = kg4[r];
    }
    __syncthreads();
    const float* bias_h = bias + h * (LW * LW);
    const int* mask_w = mask + (b & 3) * (LW * LW);
    for (int i = wv; i < LW; i += 4) {
        float s = -3.0e38f;
        if (lane < LW) {
            float a = 0.f;
#pragma unroll
            for (int r = 0; r < 8; ++r) {
                float4 qv = *(const float4*)&qs[i][r << 2];
                a += qv.x * kreg[r * 4 + 0] + qv.y * kreg[r * 4 + 1] +
                     qv.z * kreg[r * 4 + 2] + qv.w * kreg[r * 4 + 3];
            }
            s = a * SCALE_F + bias_h[i * LW + lane];
            if (mask_w[i * LW + lane] != 0) s = -100.0f;  // replace, per jnp.where
        }
        float mx = s;
#pragma unroll
        for (int off = 32; off > 0; off >>= 1) mx = fmaxf(mx, __shfl_xor(mx, off));
        float e = (lane < LW) ? __expf(s - mx) : 0.f;
        float sum = e;
#pragma unroll
        for (int off = 32; off > 0; off >>= 1) sum += __shfl_xor(sum, off);
        float p = e / sum;
        if (lane < LW) ps[wv][lane] = p;
        if (lane < HD) {
            float o = 0.f;
            for (int j = 0; j < LW; ++j) o += ps[wv][j] * vs[j][lane];
            const size_t m = (size_t)b * LW + i;
            const int c = h * HD + lane;
            u16 hb = f2bf(o);
            aoh[m * CD + c] = hb;
            aol[m * CD + c] = f2bf(o - bf2f(hb));
        }
    }
}

// ---------------------------------------------------------------------------
extern "C" void kernel_launch(void* const* d_in, const int* in_sizes, int n_in,
                              void* d_out, int out_size, void* d_ws, size_t ws_size,
                              hipStream_t stream) {
    const float* x          = (const float*)d_in[0];
    const int*   mask       = (const int*)d_in[1];
    const float* qkv_w      = (const float*)d_in[2];
    const float* proj_w     = (const float*)d_in[3];
    const float* proj_b     = (const float*)d_in[4];
    const float* rel_bias   = (const float*)d_in[5];
    const int*   rel_coords = (const int*)d_in[6];
    float* out = (float*)d_out;

    const size_t S = (size_t)NUM_B * NH * LW * HD;   // 19,267,584
    // q lives in d_out (exactly out_size floats); attn overwrites it later via proj.
    float* qp = out;
    float* kp = (float*)d_ws;                 // S fp32
    float* vp = kp + S;                       // S fp32
    float* bias = vp + S;                     // 28812 fp32
    u16* xh = (u16*)(bias + 28812);           // S bf16
    u16* xl = xh + S;                         // S bf16
    u16* wh = xl + S;                         // 442368
    u16* wl = wh + 442368;
    u16* pwh = wl + 442368;                   // 147456
    u16* pwl = pwh + 147456;
    // attn output reuses x_hi/x_lo (x is dead after qkv_gemm; stream-ordered)
    u16* aoh = xh;
    u16* aol = xl;

    convert_hilo<<<dim3((int)(S / 4 + 255) / 256), dim3(256), 0, stream>>>(x, xh, xl, (int)(S / 4));
    convert_hilo<<<dim3(432), dim3(256), 0, stream>>>(qkv_w, wh, wl, 110592);
    convert_hilo<<<dim3(144), dim3(256), 0, stream>>>(proj_w, pwh, pwl, 36864);
    bias_precompute<<<dim3((NH * LW * LW + 255) / 256), dim3(256), 0, stream>>>(rel_bias, rel_coords, bias);

    mfma_gemm<0><<<dim3(392, 9), dim3(256), 0, stream>>>(xh, xl, wh, wl, nullptr, qp, kp, vp);
    attn_kernel<<<dim3(NUM_B * NH), dim3(256), 0, stream>>>(qp, kp, vp, bias, mask, aoh, aol);
    mfma_gemm<1><<<dim3(392, 3), dim3(256), 0, stream>>>(aoh, aol, pwh, pwl, proj_b, out, nullptr, nullptr);
}

// Round 3
// 469.999 us; speedup vs baseline: 2.6063x; 1.5620x over previous
//
#include <hip/hip_runtime.h>
#include <math.h>

#define NUM_B 1024
#define LW 49
#define CD 384
#define NH 12
#define HD 32
#define SCALE_F 19.595917942265423f   // sqrt(384), faithful to reference

typedef unsigned short u16;
typedef __attribute__((ext_vector_type(8))) short short8;      // 8 bf16
typedef __attribute__((ext_vector_type(8))) _Float16 half8;    // 8 f16
typedef __attribute__((ext_vector_type(4))) float floatx4;

static __device__ __forceinline__ u16 f2bf(float f) {          // RNE f32->bf16
    unsigned u = __float_as_uint(f);
    u += 0x7fffu + ((u >> 16) & 1u);
    return (u16)(u >> 16);
}
static __device__ __forceinline__ u16 bftrunc(float f) {       // trunc f32->bf16
    return (u16)(__float_as_uint(f) >> 16);
}
static __device__ __forceinline__ float bf2f(u16 s) {
    return __uint_as_float(((unsigned)s) << 16);
}
static __device__ __forceinline__ u16 f2h_bits(float f) {      // RNE f32->f16 bits
    _Float16 h = (_Float16)f;
    u16 u;
    __builtin_memcpy(&u, &h, 2);
    return u;
}

// ---------------------------------------------------------------------------
// Split fp32 -> (hi, lo) bf16.
// ---------------------------------------------------------------------------
__global__ __launch_bounds__(256) void convert_hilo(const float* __restrict__ src,
                                                    u16* __restrict__ hi,
                                                    u16* __restrict__ lo,
                                                    int n4) {
    int idx = blockIdx.x * 256 + threadIdx.x;
    if (idx >= n4) return;
    float4 v = ((const float4*)src)[idx];
    ushort4 h, l;
    h.x = f2bf(v.x); l.x = f2bf(v.x - bf2f(h.x));
    h.y = f2bf(v.y); l.y = f2bf(v.y - bf2f(h.y));
    h.z = f2bf(v.z); l.z = f2bf(v.z - bf2f(h.z));
    h.w = f2bf(v.w); l.w = f2bf(v.w - bf2f(h.w));
    ((ushort4*)hi)[idx] = h;
    ((ushort4*)lo)[idx] = l;
}

// ---------------------------------------------------------------------------
// bm[w][h][row][lc][tn]: fused bias/mask/pad table for the MFMA attention.
//   normal  -> bias value (added to scaled logit)
//   masked  -> -1e4  (added; exp underflows to exactly 0, same as ref's -100)
//   padding -> -1e30 (row>=49 or col>=49; exp -> 0 exactly)
// Layout puts tn (col/16) innermost so attn reads one float4 per (tm,r).
// ---------------------------------------------------------------------------
__global__ __launch_bounds__(256) void bm_precompute(const float* __restrict__ rel_bias,
                                                     const int* __restrict__ rel_coords,
                                                     const int* __restrict__ mask,
                                                     float* __restrict__ bm) {
    int idx = blockIdx.x * 256 + threadIdx.x;
    if (idx >= 4 * NH * 64 * 64) return;
    int e = idx & 63;
    int tn = e & 3;
    int lcc = e >> 2;
    int col = tn * 16 + lcc;
    int row = (idx >> 6) & 63;
    int wh_ = idx >> 12;                // 0..47
    int w = wh_ / NH;
    int h = wh_ - w * NH;
    float val = -1.0e30f;
    if (row < LW && col < LW) {
        int ij = row * LW + col;
        val = mask[w * (LW * LW) + ij] ? -1.0e4f
                                       : rel_bias[rel_coords[ij] * NH + h];
    }
    bm[idx] = val;
}

// ---------------------------------------------------------------------------
// Split-bf16 MFMA GEMM (m97 structure): C[m][n] = sum_k A[m][k]*W[n][k], K=384.
// MODE 0: epilogue scatters q/k as bf16 hi/lo and v as f16, (B,H,L,hd) layout.
// MODE 1: outF[m][n] = acc + pb[n]  (fp32).
// ---------------------------------------------------------------------------
template<int MODE>
__global__ __launch_bounds__(256) void mfma_gemm(const u16* __restrict__ Ah,
                                                 const u16* __restrict__ Al,
                                                 const u16* __restrict__ Wh,
                                                 const u16* __restrict__ Wl,
                                                 const float* __restrict__ pb,
                                                 u16* __restrict__ qh_, u16* __restrict__ ql_,
                                                 u16* __restrict__ kh_, u16* __restrict__ kl_,
                                                 u16* __restrict__ vh_,
                                                 float* __restrict__ outF) {
    __shared__ u16 As_h[128 * 32];
    __shared__ u16 As_l[128 * 32];
    __shared__ u16 Bs_h[128 * 32];
    __shared__ u16 Bs_l[128 * 32];
    const int tid = threadIdx.x;
    const int w = tid >> 6;
    const int lane = tid & 63;
    const int m0 = blockIdx.x * 128;
    const int n0 = blockIdx.y * 128;
    const int quad = lane >> 4;
    const int lc = lane & 15;
    const int wrow = (w >> 1) << 6;
    const int wcol = (w & 1) << 6;
    const int srow = lane >> 2;
    const int sch = (lane & 3) * 8;

    floatx4 acc[4][4];
#pragma unroll
    for (int a = 0; a < 4; ++a)
#pragma unroll
        for (int b = 0; b < 4; ++b) acc[a][b] = (floatx4){0.f, 0.f, 0.f, 0.f};

    for (int k0 = 0; k0 < CD; k0 += 32) {
        __syncthreads();
#pragma unroll
        for (int i = 0; i < 2; ++i) {
            const int rb = w * 32 + i * 16;
            const size_t ga = (size_t)(m0 + rb + srow) * CD + k0 + sch;
            const size_t gb = (size_t)(n0 + rb + srow) * CD + k0 + sch;
            const int lof = rb * 32;
            __builtin_amdgcn_global_load_lds(
                (const __attribute__((address_space(1))) void*)(Ah + ga),
                (__attribute__((address_space(3))) void*)(As_h + lof), 16, 0, 0);
            __builtin_amdgcn_global_load_lds(
                (const __attribute__((address_space(1))) void*)(Al + ga),
                (__attribute__((address_space(3))) void*)(As_l + lof), 16, 0, 0);
            __builtin_amdgcn_global_load_lds(
                (const __attribute__((address_space(1))) void*)(Wh + gb),
                (__attribute__((address_space(3))) void*)(Bs_h + lof), 16, 0, 0);
            __builtin_amdgcn_global_load_lds(
                (const __attribute__((address_space(1))) void*)(Wl + gb),
                (__attribute__((address_space(3))) void*)(Bs_l + lof), 16, 0, 0);
        }
        __syncthreads();

        short8 af_h[4], af_l[4], bf_h[4], bf_l[4];
#pragma unroll
        for (int t = 0; t < 4; ++t) {
            const int ar = (wrow + t * 16 + lc) * 32 + quad * 8;
            af_h[t] = *(const short8*)(As_h + ar);
            af_l[t] = *(const short8*)(As_l + ar);
            const int br = (wcol + t * 16 + lc) * 32 + quad * 8;
            bf_h[t] = *(const short8*)(Bs_h + br);
            bf_l[t] = *(const short8*)(Bs_l + br);
        }
#pragma unroll
        for (int tm = 0; tm < 4; ++tm)
#pragma unroll
            for (int tn = 0; tn < 4; ++tn) {
                acc[tm][tn] = __builtin_amdgcn_mfma_f32_16x16x32_bf16(af_h[tm], bf_h[tn], acc[tm][tn], 0, 0, 0);
                acc[tm][tn] = __builtin_amdgcn_mfma_f32_16x16x32_bf16(af_h[tm], bf_l[tn], acc[tm][tn], 0, 0, 0);
                acc[tm][tn] = __builtin_amdgcn_mfma_f32_16x16x32_bf16(af_l[tm], bf_h[tn], acc[tm][tn], 0, 0, 0);
            }
    }

    if (MODE == 0) {
#pragma unroll
        for (int tn = 0; tn < 4; ++tn) {
            const int nst = n0 + wcol + tn * 16;
            const int t = nst / CD;
            const int rem = nst - t * CD;
            const int h = rem >> 5;
            const int db = (rem & 31) + lc;
#pragma unroll
            for (int tm = 0; tm < 4; ++tm)
#pragma unroll
                for (int r = 0; r < 4; ++r) {
                    const int m = m0 + wrow + tm * 16 + quad * 4 + r;
                    const int b = m / LW;
                    const int l = m - b * LW;
                    const size_t o = ((((size_t)b * NH + h) * LW + l) << 5) + db;
                    const float vv = acc[tm][tn][r];
                    if (t == 2) {
                        vh_[o] = f2h_bits(vv);
                    } else {
                        const u16 hi = bftrunc(vv);
                        const u16 lo = f2bf(vv - bf2f(hi));
                        if (t == 0) { qh_[o] = hi; ql_[o] = lo; }
                        else        { kh_[o] = hi; kl_[o] = lo; }
                    }
                }
        }
    } else {
#pragma unroll
        for (int tn = 0; tn < 4; ++tn) {
            const int n = n0 + wcol + tn * 16 + lc;
            const float bias = pb[n];
#pragma unroll
            for (int tm = 0; tm < 4; ++tm)
#pragma unroll
                for (int r = 0; r < 4; ++r) {
                    const int m = m0 + wrow + tm * 16 + quad * 4 + r;
                    outF[(size_t)m * CD + n] = acc[tm][tn][r] + bias;
                }
        }
    }
}

// ---------------------------------------------------------------------------
// MFMA attention: 1 wave per (b,h) block (wave-synchronous).
//   S (64x64, rows/cols >=49 padded): 3-term split-bf16, frags straight from
//   global (rows clamped to 48). Softmax in-register (shfl over the 16-lane
//   row groups); bias/mask/pad from the fused bm table (1 float4/(tm,r)).
//   P -> LDS as f16; V^T staged in LDS as f16; PV = 16 f16 MFMAs.
//   Output written as bf16 hi/lo, [m][C] layout, for the proj GEMM.
// ---------------------------------------------------------------------------
__global__ __launch_bounds__(64) void attn_mfma(const u16* __restrict__ qh,
                                                const u16* __restrict__ ql,
                                                const u16* __restrict__ kh,
                                                const u16* __restrict__ kl,
                                                const u16* __restrict__ vh,
                                                const float* __restrict__ bm,
                                                u16* __restrict__ aoh,
                                                u16* __restrict__ aol) {
    const int bh = blockIdx.x;
    const int b = bh / NH;
    const int h = bh - b * NH;
    const int lane = threadIdx.x;
    const int quad = lane >> 4;
    const int lc = lane & 15;
    __shared__ u16 Vt[32 * 72];   // V^T, f16 bits; stride 72 (16B-aligned, ~2-way banks)
    __shared__ u16 Ps[64 * 72];   // P, f16 bits

    const size_t base = (size_t)bh * (LW * HD);

    // Q (A-op) / K (B-op) fragments, bf16 hi/lo; rows clamped to 48 (no OOB)
    short8 aQh[4], aQl[4], bKh[4], bKl[4];
#pragma unroll
    for (int t = 0; t < 4; ++t) {
        int row = t * 16 + lc; if (row > 48) row = 48;
        const size_t o = base + (size_t)row * HD + quad * 8;
        aQh[t] = *(const short8*)(qh + o);
        aQl[t] = *(const short8*)(ql + o);
        bKh[t] = *(const short8*)(kh + o);
        bKl[t] = *(const short8*)(kl + o);
    }
    // stage V^T: Vt[d][j] = v[min(j,48)][d]  (j>=49 finite garbage, killed by p=0)
#pragma unroll
    for (int it = 0; it < 4; ++it) {
        const int idx = lane + it * 64;        // 0..255 = 64 rows x 4 chunks
        const int j = idx >> 2;
        const int jc = j > 48 ? 48 : j;
        const int ch = (idx & 3) * 8;
        short8 vv = *(const short8*)(vh + base + (size_t)jc * HD + ch);
#pragma unroll
        for (int e = 0; e < 8; ++e) Vt[(ch + e) * 72 + j] = (u16)vv[e];
    }

    // S = Q K^T (hi*hi + hi*lo + lo*hi)
    floatx4 acc[4][4];
#pragma unroll
    for (int a = 0; a < 4; ++a)
#pragma unroll
        for (int c = 0; c < 4; ++c) acc[a][c] = (floatx4){0.f, 0.f, 0.f, 0.f};
#pragma unroll
    for (int tm = 0; tm < 4; ++tm)
#pragma unroll
        for (int tn = 0; tn < 4; ++tn) {
            acc[tm][tn] = __builtin_amdgcn_mfma_f32_16x16x32_bf16(aQh[tm], bKh[tn], acc[tm][tn], 0, 0, 0);
            acc[tm][tn] = __builtin_amdgcn_mfma_f32_16x16x32_bf16(aQh[tm], bKl[tn], acc[tm][tn], 0, 0, 0);
            acc[tm][tn] = __builtin_amdgcn_mfma_f32_16x16x32_bf16(aQl[tm], bKh[tn], acc[tm][tn], 0, 0, 0);
        }

    // softmax per row; P (f16) into LDS
    const float* bmp = bm + (((size_t)(b & 3) * NH + h) << 12);
#pragma unroll
    for (int tm = 0; tm < 4; ++tm)
#pragma unroll
        for (int r = 0; r < 4; ++r) {
            const int row = tm * 16 + quad * 4 + r;
            const float4 bv = *(const float4*)(bmp + row * 64 + lc * 4);
            const float s0 = fmaf(acc[tm][0][r], SCALE_F, bv.x);
            const float s1 = fmaf(acc[tm][1][r], SCALE_F, bv.y);
            const float s2 = fmaf(acc[tm][2][r], SCALE_F, bv.z);
            const float s3 = fmaf(acc[tm][3][r], SCALE_F, bv.w);
            float mx = fmaxf(fmaxf(s0, s1), fmaxf(s2, s3));
#pragma unroll
            for (int off = 1; off < 16; off <<= 1) mx = fmaxf(mx, __shfl_xor(mx, off));
            const float e0 = __expf(s0 - mx);
            const float e1 = __expf(s1 - mx);
            const float e2 = __expf(s2 - mx);
            const float e3 = __expf(s3 - mx);
            float sum = (e0 + e1) + (e2 + e3);
#pragma unroll
            for (int off = 1; off < 16; off <<= 1) sum += __shfl_xor(sum, off);
            const float inv = __builtin_amdgcn_rcpf(sum);
            Ps[row * 72 +  0 + lc] = f2h_bits(e0 * inv);
            Ps[row * 72 + 16 + lc] = f2h_bits(e1 * inv);
            Ps[row * 72 + 32 + lc] = f2h_bits(e2 * inv);
            Ps[row * 72 + 48 + lc] = f2h_bits(e3 * inv);
        }

    __syncthreads();   // single wave: just orders LDS writes before reads

    // O = P V  (f16 MFMA, K=64 in 2 steps, N=32 in 2 tiles)
    floatx4 o[4][2];
#pragma unroll
    for (int a = 0; a < 4; ++a) { o[a][0] = (floatx4){0.f,0.f,0.f,0.f}; o[a][1] = (floatx4){0.f,0.f,0.f,0.f}; }
#pragma unroll
    for (int ks = 0; ks < 2; ++ks) {
        const half8 bV0 = *(const half8*)(Vt + (lc) * 72 + ks * 32 + quad * 8);
        const half8 bV1 = *(const half8*)(Vt + (16 + lc) * 72 + ks * 32 + quad * 8);
#pragma unroll
        for (int tm = 0; tm < 4; ++tm) {
            const half8 aP = *(const half8*)(Ps + (tm * 16 + lc) * 72 + ks * 32 + quad * 8);
            o[tm][0] = __builtin_amdgcn_mfma_f32_16x16x32_f16(aP, bV0, o[tm][0], 0, 0, 0);
            o[tm][1] = __builtin_amdgcn_mfma_f32_16x16x32_f16(aP, bV1, o[tm][1], 0, 0, 0);
        }
    }
    // write out as bf16 hi/lo, [m][C] layout (c = h*32 + d)
#pragma unroll
    for (int tm = 0; tm < 4; ++tm)
#pragma unroll
        for (int r = 0; r < 4; ++r) {
            const int i = tm * 16 + quad * 4 + r;
            if (i < LW) {
#pragma unroll
                for (int tn = 0; tn < 2; ++tn) {
                    const float v = o[tm][tn][r];
                    const u16 hi = bftrunc(v);
                    const u16 lo = f2bf(v - bf2f(hi));
                    const size_t mm = ((size_t)b * LW + i) * CD + h * HD + tn * 16 + lc;
                    aoh[mm] = hi;
                    aol[mm] = lo;
                }
            }
        }
}

// ---------------------------------------------------------------------------
extern "C" void kernel_launch(void* const* d_in, const int* in_sizes, int n_in,
                              void* d_out, int out_size, void* d_ws, size_t ws_size,
                              hipStream_t stream) {
    const float* x          = (const float*)d_in[0];
    const int*   mask       = (const int*)d_in[1];
    const float* qkv_w      = (const float*)d_in[2];
    const float* proj_w     = (const float*)d_in[3];
    const float* proj_b     = (const float*)d_in[4];
    const float* rel_bias   = (const float*)d_in[5];
    const int*   rel_coords = (const int*)d_in[6];
    float* out = (float*)d_out;

    const size_t S = (size_t)NUM_B * NH * LW * HD;   // 19,267,584
    // ws: xh|xl|kh|kl|vh|wh|wl|pwh|pwl|bm  ~ 195.8 MB
    u16* xh  = (u16*)d_ws;
    u16* xl  = xh + S;
    u16* kh  = xl + S;
    u16* kl  = kh + S;
    u16* vh  = kl + S;
    u16* wh  = vh + S;                    // 442368
    u16* wl  = wh + 442368;
    u16* pwh = wl + 442368;               // 147456
    u16* pwl = pwh + 147456;
    float* bm = (float*)(pwl + 147456);   // 196608 floats
    // q hi/lo lives in d_out (2*S u16 = out_size fp32 exactly); dead before proj writes
    u16* qh = (u16*)d_out;
    u16* ql = qh + S;
    // attn output reuses xh/xl (x dead after qkv_gemm)
    u16* aoh = xh;
    u16* aol = xl;

    convert_hilo<<<dim3((int)(S / 4 + 255) / 256), dim3(256), 0, stream>>>(x, xh, xl, (int)(S / 4));
    convert_hilo<<<dim3(432), dim3(256), 0, stream>>>(qkv_w, wh, wl, 110592);
    convert_hilo<<<dim3(144), dim3(256), 0, stream>>>(proj_w, pwh, pwl, 36864);
    bm_precompute<<<dim3(768), dim3(256), 0, stream>>>(rel_bias, rel_coords, mask, bm);

    mfma_gemm<0><<<dim3(392, 9), dim3(256), 0, stream>>>(xh, xl, wh, wl, nullptr,
                                                         qh, ql, kh, kl, vh, nullptr);
    attn_mfma<<<dim3(NUM_B * NH), dim3(64), 0, stream>>>(qh, ql, kh, kl, vh, bm, aoh, aol);
    mfma_gemm<1><<<dim3(392, 3), dim3(256), 0, stream>>>(aoh, aol, pwh, pwl, proj_b,
                                                         nullptr, nullptr, nullptr, nullptr, nullptr, out);
}

// Round 4
// 423.363 us; speedup vs baseline: 2.8934x; 1.1102x over previous
//
#include <hip/hip_runtime.h>
#include <math.h>

#define NUM_B 1024
#define LW 49
#define CD 384
#define NH 12
#define HD 32
#define SCALE_F 19.595917942265423f   // sqrt(384), faithful to reference

typedef unsigned short u16;
typedef unsigned int u32;
typedef __attribute__((ext_vector_type(8))) short short8;      // 8 bf16
typedef __attribute__((ext_vector_type(8))) _Float16 half8;    // 8 f16
typedef __attribute__((ext_vector_type(4))) float floatx4;

static __device__ __forceinline__ u16 f2bf(float f) {          // RNE f32->bf16
    unsigned u = __float_as_uint(f);
    u += 0x7fffu + ((u >> 16) & 1u);
    return (u16)(u >> 16);
}
static __device__ __forceinline__ float bf2f(u16 s) {
    return __uint_as_float(((unsigned)s) << 16);
}
static __device__ __forceinline__ u16 f2h_bits(float f) {      // RNE f32->f16 bits
    _Float16 h = (_Float16)f;
    u16 u;
    __builtin_memcpy(&u, &h, 2);
    return u;
}

// ---------------------------------------------------------------------------
// Fused prologue (1 launch): x -> bf16 hi/lo; qkv_w -> bf16 hi/lo;
// proj_w -> f16 hi/lo; bm table (bias/mask/pad fused, tn-innermost layout).
// ---------------------------------------------------------------------------
#define X4 4816896     // S/4
#define W4 110592
#define P4 36864
#define BM4 49152
__global__ __launch_bounds__(256) void prep(const float* __restrict__ x,
                                            const float* __restrict__ qkv_w,
                                            const float* __restrict__ proj_w,
                                            const float* __restrict__ rel_bias,
                                            const int* __restrict__ rel_coords,
                                            const int* __restrict__ mask,
                                            u16* __restrict__ xbh, u16* __restrict__ xbl,
                                            u16* __restrict__ wbh, u16* __restrict__ wbl,
                                            u16* __restrict__ pfh, u16* __restrict__ pfl,
                                            float* __restrict__ bm) {
    int idx = blockIdx.x * 256 + threadIdx.x;
    if (idx < X4) {
        float4 v = ((const float4*)x)[idx];
        ushort4 h, l;
        h.x = f2bf(v.x); l.x = f2bf(v.x - bf2f(h.x));
        h.y = f2bf(v.y); l.y = f2bf(v.y - bf2f(h.y));
        h.z = f2bf(v.z); l.z = f2bf(v.z - bf2f(h.z));
        h.w = f2bf(v.w); l.w = f2bf(v.w - bf2f(h.w));
        ((ushort4*)xbh)[idx] = h;
        ((ushort4*)xbl)[idx] = l;
    } else if (idx < X4 + W4) {
        int i = idx - X4;
        float4 v = ((const float4*)qkv_w)[i];
        ushort4 h, l;
        h.x = f2bf(v.x); l.x = f2bf(v.x - bf2f(h.x));
        h.y = f2bf(v.y); l.y = f2bf(v.y - bf2f(h.y));
        h.z = f2bf(v.z); l.z = f2bf(v.z - bf2f(h.z));
        h.w = f2bf(v.w); l.w = f2bf(v.w - bf2f(h.w));
        ((ushort4*)wbh)[i] = h;
        ((ushort4*)wbl)[i] = l;
    } else if (idx < X4 + W4 + P4) {
        int i = idx - (X4 + W4);
        float4 v = ((const float4*)proj_w)[i];
        ushort4 h, l;
        h.x = f2h_bits(v.x); l.x = f2h_bits(v.x - (float)(_Float16)v.x);
        h.y = f2h_bits(v.y); l.y = f2h_bits(v.y - (float)(_Float16)v.y);
        h.z = f2h_bits(v.z); l.z = f2h_bits(v.z - (float)(_Float16)v.z);
        h.w = f2h_bits(v.w); l.w = f2h_bits(v.w - (float)(_Float16)v.w);
        ((ushort4*)pfh)[i] = h;
        ((ushort4*)pfl)[i] = l;
    } else if (idx < X4 + W4 + P4 + BM4) {
        int t = idx - (X4 + W4 + P4);
        float4 o;
        float* op = (float*)&o;
#pragma unroll
        for (int i = 0; i < 4; ++i) {
            int j = t * 4 + i;                 // bm flat index
            int e = j & 63;
            int col = (e & 3) * 16 + (e >> 2); // tn*16 + lc
            int row = (j >> 6) & 63;
            int wh_ = j >> 12;                 // 0..47
            int w = wh_ / NH;
            int h = wh_ - w * NH;
            float val = -1.0e30f;
            if (row < LW && col < LW) {
                int ij = row * LW + col;
                val = mask[w * (LW * LW) + ij] ? -1.0e4f
                                               : rel_bias[rel_coords[ij] * NH + h];
            }
            op[i] = val;
        }
        ((float4*)bm)[t] = o;
    }
}

// ---------------------------------------------------------------------------
// QKV GEMM (split-bf16): q/k tiles (y<6) 3-term; v tiles (y>=6) 1-term,
// lo staging skipped. Epilogue: q/k packed u32 (hi|lo), v as f16.
// ---------------------------------------------------------------------------
__global__ __launch_bounds__(256) void qkv_gemm(const u16* __restrict__ Ah,
                                                const u16* __restrict__ Al,
                                                const u16* __restrict__ Wh,
                                                const u16* __restrict__ Wl,
                                                u32* __restrict__ qp,
                                                u32* __restrict__ kp,
                                                u16* __restrict__ vp) {
    __shared__ u16 As_h[128 * 32];
    __shared__ u16 As_l[128 * 32];
    __shared__ u16 Bs_h[128 * 32];
    __shared__ u16 Bs_l[128 * 32];
    const int tid = threadIdx.x;
    const int w = tid >> 6;
    const int lane = tid & 63;
    const int m0 = blockIdx.x * 128;
    const int n0 = blockIdx.y * 128;
    const int quad = lane >> 4;
    const int lc = lane & 15;
    const int wrow = (w >> 1) << 6;
    const int wcol = (w & 1) << 6;
    const int srow = lane >> 2;
    const int sch = (lane & 3) * 8;
    const bool vblk = (blockIdx.y >= 6);

    floatx4 acc[4][4];
#pragma unroll
    for (int a = 0; a < 4; ++a)
#pragma unroll
        for (int b = 0; b < 4; ++b) acc[a][b] = (floatx4){0.f, 0.f, 0.f, 0.f};

    for (int k0 = 0; k0 < CD; k0 += 32) {
        __syncthreads();
#pragma unroll
        for (int i = 0; i < 2; ++i) {
            const int rb = w * 32 + i * 16;
            const size_t ga = (size_t)(m0 + rb + srow) * CD + k0 + sch;
            const size_t gb = (size_t)(n0 + rb + srow) * CD + k0 + sch;
            const int lof = rb * 32;
            __builtin_amdgcn_global_load_lds(
                (const __attribute__((address_space(1))) void*)(Ah + ga),
                (__attribute__((address_space(3))) void*)(As_h + lof), 16, 0, 0);
            __builtin_amdgcn_global_load_lds(
                (const __attribute__((address_space(1))) void*)(Wh + gb),
                (__attribute__((address_space(3))) void*)(Bs_h + lof), 16, 0, 0);
            if (!vblk) {
                __builtin_amdgcn_global_load_lds(
                    (const __attribute__((address_space(1))) void*)(Al + ga),
                    (__attribute__((address_space(3))) void*)(As_l + lof), 16, 0, 0);
                __builtin_amdgcn_global_load_lds(
                    (const __attribute__((address_space(1))) void*)(Wl + gb),
                    (__attribute__((address_space(3))) void*)(Bs_l + lof), 16, 0, 0);
            }
        }
        __syncthreads();

        if (!vblk) {
            short8 af_h[4], af_l[4], bf_h[4], bf_l[4];
#pragma unroll
            for (int t = 0; t < 4; ++t) {
                const int ar = (wrow + t * 16 + lc) * 32 + quad * 8;
                af_h[t] = *(const short8*)(As_h + ar);
                af_l[t] = *(const short8*)(As_l + ar);
                const int br = (wcol + t * 16 + lc) * 32 + quad * 8;
                bf_h[t] = *(const short8*)(Bs_h + br);
                bf_l[t] = *(const short8*)(Bs_l + br);
            }
#pragma unroll
            for (int tm = 0; tm < 4; ++tm)
#pragma unroll
                for (int tn = 0; tn < 4; ++tn) {
                    acc[tm][tn] = __builtin_amdgcn_mfma_f32_16x16x32_bf16(af_h[tm], bf_h[tn], acc[tm][tn], 0, 0, 0);
                    acc[tm][tn] = __builtin_amdgcn_mfma_f32_16x16x32_bf16(af_h[tm], bf_l[tn], acc[tm][tn], 0, 0, 0);
                    acc[tm][tn] = __builtin_amdgcn_mfma_f32_16x16x32_bf16(af_l[tm], bf_h[tn], acc[tm][tn], 0, 0, 0);
                }
        } else {
            short8 af_h[4], bf_h[4];
#pragma unroll
            for (int t = 0; t < 4; ++t) {
                af_h[t] = *(const short8*)(As_h + (wrow + t * 16 + lc) * 32 + quad * 8);
                bf_h[t] = *(const short8*)(Bs_h + (wcol + t * 16 + lc) * 32 + quad * 8);
            }
#pragma unroll
            for (int tm = 0; tm < 4; ++tm)
#pragma unroll
                for (int tn = 0; tn < 4; ++tn)
                    acc[tm][tn] = __builtin_amdgcn_mfma_f32_16x16x32_bf16(af_h[tm], bf_h[tn], acc[tm][tn], 0, 0, 0);
        }
    }

    // epilogue: D col = lane&15, row = quad*4 + reg
#pragma unroll
    for (int tn = 0; tn < 4; ++tn) {
        const int nst = n0 + wcol + tn * 16;
        const int t = nst / CD;
        const int rem = nst - t * CD;
        const int h = rem >> 5;
        const int db = (rem & 31) + lc;
#pragma unroll
        for (int tm = 0; tm < 4; ++tm)
#pragma unroll
            for (int r = 0; r < 4; ++r) {
                const int m = m0 + wrow + tm * 16 + quad * 4 + r;
                const int b = m / LW;
                const int l = m - b * LW;
                const size_t o = ((((size_t)b * NH + h) * LW + l) << 5) + db;
                const float vv = acc[tm][tn][r];
                if (t == 2) {
                    vp[o] = f2h_bits(vv);
                } else {
                    const unsigned bits = __float_as_uint(vv);
                    const unsigned hi_high = bits & 0xffff0000u;
                    const u16 lo = f2bf(vv - __uint_as_float(hi_high));
                    const u32 packed = hi_high | (u32)lo;
                    if (t == 0) qp[o] = packed; else kp[o] = packed;
                }
            }
    }
}

// ---------------------------------------------------------------------------
// Proj GEMM (f16 2-term): out[m][n] = sum_k A[m][k]*(Wh+Wl)[n][k] + pb[n].
// A = attn output stored as f16 (exact-as-stored); W = f16 hi/lo split.
// ---------------------------------------------------------------------------
__global__ __launch_bounds__(256) void proj_gemm(const u16* __restrict__ Af,
                                                 const u16* __restrict__ Wfh,
                                                 const u16* __restrict__ Wfl,
                                                 const float* __restrict__ pb,
                                                 float* __restrict__ outF) {
    __shared__ u16 As_f[128 * 32];
    __shared__ u16 Bs_h[128 * 32];
    __shared__ u16 Bs_l[128 * 32];
    const int tid = threadIdx.x;
    const int w = tid >> 6;
    const int lane = tid & 63;
    const int m0 = blockIdx.x * 128;
    const int n0 = blockIdx.y * 128;
    const int quad = lane >> 4;
    const int lc = lane & 15;
    const int wrow = (w >> 1) << 6;
    const int wcol = (w & 1) << 6;
    const int srow = lane >> 2;
    const int sch = (lane & 3) * 8;

    floatx4 acc[4][4];
#pragma unroll
    for (int a = 0; a < 4; ++a)
#pragma unroll
        for (int b = 0; b < 4; ++b) acc[a][b] = (floatx4){0.f, 0.f, 0.f, 0.f};

    for (int k0 = 0; k0 < CD; k0 += 32) {
        __syncthreads();
#pragma unroll
        for (int i = 0; i < 2; ++i) {
            const int rb = w * 32 + i * 16;
            const size_t ga = (size_t)(m0 + rb + srow) * CD + k0 + sch;
            const size_t gb = (size_t)(n0 + rb + srow) * CD + k0 + sch;
            const int lof = rb * 32;
            __builtin_amdgcn_global_load_lds(
                (const __attribute__((address_space(1))) void*)(Af + ga),
                (__attribute__((address_space(3))) void*)(As_f + lof), 16, 0, 0);
            __builtin_amdgcn_global_load_lds(
                (const __attribute__((address_space(1))) void*)(Wfh + gb),
                (__attribute__((address_space(3))) void*)(Bs_h + lof), 16, 0, 0);
            __builtin_amdgcn_global_load_lds(
                (const __attribute__((address_space(1))) void*)(Wfl + gb),
                (__attribute__((address_space(3))) void*)(Bs_l + lof), 16, 0, 0);
        }
        __syncthreads();

        half8 af[4], bh[4], bl[4];
#pragma unroll
        for (int t = 0; t < 4; ++t) {
            af[t] = *(const half8*)(As_f + (wrow + t * 16 + lc) * 32 + quad * 8);
            const int br = (wcol + t * 16 + lc) * 32 + quad * 8;
            bh[t] = *(const half8*)(Bs_h + br);
            bl[t] = *(const half8*)(Bs_l + br);
        }
#pragma unroll
        for (int tm = 0; tm < 4; ++tm)
#pragma unroll
            for (int tn = 0; tn < 4; ++tn) {
                acc[tm][tn] = __builtin_amdgcn_mfma_f32_16x16x32_f16(af[tm], bh[tn], acc[tm][tn], 0, 0, 0);
                acc[tm][tn] = __builtin_amdgcn_mfma_f32_16x16x32_f16(af[tm], bl[tn], acc[tm][tn], 0, 0, 0);
            }
    }
#pragma unroll
    for (int tn = 0; tn < 4; ++tn) {
        const int n = n0 + wcol + tn * 16 + lc;
        const float bias = pb[n];
#pragma unroll
        for (int tm = 0; tm < 4; ++tm)
#pragma unroll
            for (int r = 0; r < 4; ++r) {
                const int m = m0 + wrow + tm * 16 + quad * 4 + r;
                outF[(size_t)m * CD + n] = acc[tm][tn][r] + bias;
            }
    }
}

// ---------------------------------------------------------------------------
// MFMA attention: 1 wave per (b,h). q/k packed u32 (hi|lo bf16) from global;
// S = 3-term split-bf16; in-register softmax; P,V^T f16 in LDS; PV f16 MFMA.
// Output: single f16, [m][C] layout for the proj GEMM.
// ---------------------------------------------------------------------------
__global__ __launch_bounds__(64) void attn_mfma(const u32* __restrict__ qp,
                                                const u32* __restrict__ kp,
                                                const u16* __restrict__ vh,
                                                const float* __restrict__ bm,
                                                u16* __restrict__ aof) {
    const int bh = blockIdx.x;
    const int b = bh / NH;
    const int h = bh - b * NH;
    const int lane = threadIdx.x;
    const int quad = lane >> 4;
    const int lc = lane & 15;
    __shared__ u16 Vt[32 * 72];
    __shared__ u16 Ps[64 * 72];

    const size_t base = (size_t)bh * (LW * HD);

    short8 aQh[4], aQl[4], bKh[4], bKl[4];
#pragma unroll
    for (int t = 0; t < 4; ++t) {
        int row = t * 16 + lc; if (row > 48) row = 48;
        const size_t o = base + (size_t)row * HD + quad * 8;
        uint4 q0 = *(const uint4*)(qp + o);
        uint4 q1 = *(const uint4*)(qp + o + 4);
        uint4 k0 = *(const uint4*)(kp + o);
        uint4 k1 = *(const uint4*)(kp + o + 4);
        const unsigned* qw = (const unsigned*)&q0;   // q0,q1 contiguous on stack? use explicit
        unsigned qv[8] = {q0.x, q0.y, q0.z, q0.w, q1.x, q1.y, q1.z, q1.w};
        unsigned kv[8] = {k0.x, k0.y, k0.z, k0.w, k1.x, k1.y, k1.z, k1.w};
        (void)qw;
#pragma unroll
        for (int e = 0; e < 8; ++e) {
            aQh[t][e] = (short)(qv[e] >> 16);
            aQl[t][e] = (short)(qv[e] & 0xffffu);
            bKh[t][e] = (short)(kv[e] >> 16);
            bKl[t][e] = (short)(kv[e] & 0xffffu);
        }
    }
    // stage V^T (f16): Vt[d][j] = v[min(j,48)][d]
#pragma unroll
    for (int it = 0; it < 4; ++it) {
        const int idx = lane + it * 64;
        const int j = idx >> 2;
        const int jc = j > 48 ? 48 : j;
        const int ch = (idx & 3) * 8;
        short8 vv = *(const short8*)(vh + base + (size_t)jc * HD + ch);
#pragma unroll
        for (int e = 0; e < 8; ++e) Vt[(ch + e) * 72 + j] = (u16)vv[e];
    }

    floatx4 acc[4][4];
#pragma unroll
    for (int a = 0; a < 4; ++a)
#pragma unroll
        for (int c = 0; c < 4; ++c) acc[a][c] = (floatx4){0.f, 0.f, 0.f, 0.f};
#pragma unroll
    for (int tm = 0; tm < 4; ++tm)
#pragma unroll
        for (int tn = 0; tn < 4; ++tn) {
            acc[tm][tn] = __builtin_amdgcn_mfma_f32_16x16x32_bf16(aQh[tm], bKh[tn], acc[tm][tn], 0, 0, 0);
            acc[tm][tn] = __builtin_amdgcn_mfma_f32_16x16x32_bf16(aQh[tm], bKl[tn], acc[tm][tn], 0, 0, 0);
            acc[tm][tn] = __builtin_amdgcn_mfma_f32_16x16x32_bf16(aQl[tm], bKh[tn], acc[tm][tn], 0, 0, 0);
        }

    const float* bmp = bm + (((size_t)(b & 3) * NH + h) << 12);
#pragma unroll
    for (int tm = 0; tm < 4; ++tm)
#pragma unroll
        for (int r = 0; r < 4; ++r) {
            const int row = tm * 16 + quad * 4 + r;
            const float4 bv = *(const float4*)(bmp + row * 64 + lc * 4);
            const float s0 = fmaf(acc[tm][0][r], SCALE_F, bv.x);
            const float s1 = fmaf(acc[tm][1][r], SCALE_F, bv.y);
            const float s2 = fmaf(acc[tm][2][r], SCALE_F, bv.z);
            const float s3 = fmaf(acc[tm][3][r], SCALE_F, bv.w);
            float mx = fmaxf(fmaxf(s0, s1), fmaxf(s2, s3));
#pragma unroll
            for (int off = 1; off < 16; off <<= 1) mx = fmaxf(mx, __shfl_xor(mx, off));
            const float e0 = __expf(s0 - mx);
            const float e1 = __expf(s1 - mx);
            const float e2 = __expf(s2 - mx);
            const float e3 = __expf(s3 - mx);
            float sum = (e0 + e1) + (e2 + e3);
#pragma unroll
            for (int off = 1; off < 16; off <<= 1) sum += __shfl_xor(sum, off);
            const float inv = __builtin_amdgcn_rcpf(sum);
            Ps[row * 72 +  0 + lc] = f2h_bits(e0 * inv);
            Ps[row * 72 + 16 + lc] = f2h_bits(e1 * inv);
            Ps[row * 72 + 32 + lc] = f2h_bits(e2 * inv);
            Ps[row * 72 + 48 + lc] = f2h_bits(e3 * inv);
        }

    __syncthreads();

    floatx4 o[4][2];
#pragma unroll
    for (int a = 0; a < 4; ++a) { o[a][0] = (floatx4){0.f,0.f,0.f,0.f}; o[a][1] = (floatx4){0.f,0.f,0.f,0.f}; }
#pragma unroll
    for (int ks = 0; ks < 2; ++ks) {
        const half8 bV0 = *(const half8*)(Vt + (lc) * 72 + ks * 32 + quad * 8);
        const half8 bV1 = *(const half8*)(Vt + (16 + lc) * 72 + ks * 32 + quad * 8);
#pragma unroll
        for (int tm = 0; tm < 4; ++tm) {
            const half8 aP = *(const half8*)(Ps + (tm * 16 + lc) * 72 + ks * 32 + quad * 8);
            o[tm][0] = __builtin_amdgcn_mfma_f32_16x16x32_f16(aP, bV0, o[tm][0], 0, 0, 0);
            o[tm][1] = __builtin_amdgcn_mfma_f32_16x16x32_f16(aP, bV1, o[tm][1], 0, 0, 0);
        }
    }
#pragma unroll
    for (int tm = 0; tm < 4; ++tm)
#pragma unroll
        for (int r = 0; r < 4; ++r) {
            const int i = tm * 16 + quad * 4 + r;
            if (i < LW) {
#pragma unroll
                for (int tn = 0; tn < 2; ++tn) {
                    const size_t mm = ((size_t)b * LW + i) * CD + h * HD + tn * 16 + lc;
                    aof[mm] = f2h_bits(o[tm][tn][r]);
                }
            }
        }
}

// ---------------------------------------------------------------------------
extern "C" void kernel_launch(void* const* d_in, const int* in_sizes, int n_in,
                              void* d_out, int out_size, void* d_ws, size_t ws_size,
                              hipStream_t stream) {
    const float* x          = (const float*)d_in[0];
    const int*   mask       = (const int*)d_in[1];
    const float* qkv_w      = (const float*)d_in[2];
    const float* proj_w     = (const float*)d_in[3];
    const float* proj_b     = (const float*)d_in[4];
    const float* rel_bias   = (const float*)d_in[5];
    const int*   rel_coords = (const int*)d_in[6];
    float* out = (float*)d_out;

    const size_t S = (size_t)NUM_B * NH * LW * HD;   // 19,267,584
    // ws (u16 units): xbh S | xbl S | kp 2S | vh S | wbh/wbl | pfh/pfl | bm
    u16* xbh = (u16*)d_ws;
    u16* xbl = xbh + S;
    u32* kp  = (u32*)(xbl + S);           // S u32
    u16* vh  = (u16*)(kp + S);            // S u16
    u16* wbh = vh + S;                    // 442368
    u16* wbl = wbh + 442368;
    u16* pfh = wbl + 442368;              // 147456
    u16* pfl = pfh + 147456;
    float* bm = (float*)(pfl + 147456);   // 196608 floats
    // q packed lives in d_out (S u32 == out_size f32); dead before proj writes
    u32* qp = (u32*)d_out;
    // attn f16 output reuses xbh (x dead after qkv_gemm)
    u16* aof = xbh;

    prep<<<dim3(19584), dim3(256), 0, stream>>>(x, qkv_w, proj_w, rel_bias, rel_coords,
                                                mask, xbh, xbl, wbh, wbl, pfh, pfl, bm);
    qkv_gemm<<<dim3(392, 9), dim3(256), 0, stream>>>(xbh, xbl, wbh, wbl, qp, kp, vh);
    attn_mfma<<<dim3(NUM_B * NH), dim3(64), 0, stream>>>(qp, kp, vh, bm, aof);
    proj_gemm<<<dim3(392, 3), dim3(256), 0, stream>>>(aof, pfh, pfl, proj_b, out);
}